// Round 7
// baseline (97.475 us; speedup 1.0000x reference)
//
#include <hip/hip_runtime.h>
#include <hip/hip_bf16.h>
#include <math.h>

// Problem constants: B=32, S=16, D=64, E=768
#define EPSF 1e-12f

typedef short bf16x8 __attribute__((ext_vector_type(8)));
typedef float f32x4  __attribute__((ext_vector_type(4)));

// tanh-approx GELU via native exp2/rcp: max abs err ~3e-4 vs exact erf-gelu.
__device__ __forceinline__ float gelu_fast(float x) {
    float x2 = x * x;
    float z = -2.3021184f * x * fmaf(0.044715f, x2, 1.0f);
    float u = __builtin_amdgcn_exp2f(z);
    return x * __builtin_amdgcn_rcpf(1.0f + u);
}
__device__ __forceinline__ float sigmoid_fast(float x) {
    float u = __builtin_amdgcn_exp2f(-1.44269504f * x);
    return __builtin_amdgcn_rcpf(1.0f + u);
}
__device__ __forceinline__ float bf2f(unsigned short u) {
    return __uint_as_float(((unsigned int)u) << 16);
}
__device__ __forceinline__ unsigned short f2bf(float f) {
    unsigned int u = __float_as_uint(f);
    u += 0x7FFFu + ((u >> 16) & 1u);     // RNE
    return (unsigned short)(u >> 16);
}

// ---------------------------------------------------------------------------
// k_prep: blocks [0,640) = norms+bf16-cvt (4 rows/block); [640,1000) =
// W1/W2 transpose+cvt tiles.
// ---------------------------------------------------------------------------
__global__ __launch_bounds__(256) void k_prep(
    const float* __restrict__ doc, const float* __restrict__ seg,
    const float* __restrict__ W1, const float* __restrict__ W2,
    float* __restrict__ dscale, float* __restrict__ sscale,
    float* __restrict__ smean, float* __restrict__ cscale,
    unsigned short* __restrict__ docB, unsigned short* __restrict__ segB,
    unsigned short* __restrict__ W1T, unsigned short* __restrict__ W2T)
{
    __shared__ float sT[64][65];
    int blk = blockIdx.x;
    int t = threadIdx.x;
    if (blk < 640) {
        int row = blk * 4 + (t >> 6);
        int lane = t & 63;
        const float* src = (row < 2048) ? (doc + (size_t)row * 768)
                                        : (seg + (size_t)(row - 2048) * 768);
        unsigned short* dst = (row < 2048) ? (docB + (size_t)row * 768)
                                           : (segB + (size_t)(row - 2048) * 768);
        float ss = 0.f, sm = 0.f;
        float xv[12];
        #pragma unroll
        for (int i = 0; i < 12; ++i) {
            float x = src[lane + 64 * i];
            xv[i] = x;
            ss += x * x; sm += x;
        }
        #pragma unroll
        for (int i = 0; i < 12; ++i) dst[lane + 64 * i] = f2bf(xv[i]);
        #pragma unroll
        for (int off = 32; off > 0; off >>= 1) {
            ss += __shfl_down(ss, off);
            sm += __shfl_down(sm, off);
        }
        if (lane == 0) {
            if (row < 2048) {
                dscale[row] = rsqrtf(fmaxf(ss, EPSF));
            } else {
                int r = row - 2048;
                sscale[r] = rsqrtf(fmaxf(ss, EPSF));
                float mean = sm * (1.0f / 768.0f);
                smean[r] = mean;
                cscale[r] = rsqrtf(fmaxf(ss - sm * mean, EPSF));
            }
        }
        return;
    }
    // transpose tiles
    int tt = blk - 640;
    const float* in; unsigned short* out; int R, C, bx, by;
    if (tt < 288) { in = W1; out = W1T; R = 1536; C = 768; bx = tt % 12; by = tt / 12; }
    else { tt -= 288; in = W2; out = W2T; R = 768; C = 384; bx = tt % 6; by = tt / 6; }
    int c0 = bx * 64, r0 = by * 64;
    int tr = t >> 2, tc4 = (t & 3) * 16;
    #pragma unroll
    for (int i = 0; i < 4; ++i) {
        float4 v = *(const float4*)(in + (size_t)(r0 + tr) * C + c0 + tc4 + i * 4);
        sT[tr][tc4 + i * 4 + 0] = v.x; sT[tr][tc4 + i * 4 + 1] = v.y;
        sT[tr][tc4 + i * 4 + 2] = v.z; sT[tr][tc4 + i * 4 + 3] = v.w;
    }
    __syncthreads();
    union { uint4 v; unsigned short u[8]; } o0, o1;
    #pragma unroll
    for (int i = 0; i < 8; ++i) o0.u[i] = f2bf(sT[tc4 + i][tr]);
    #pragma unroll
    for (int i = 0; i < 8; ++i) o1.u[i] = f2bf(sT[tc4 + 8 + i][tr]);
    *(uint4*)(out + (size_t)(c0 + tr) * R + r0 + tc4) = o0.v;
    *(uint4*)(out + (size_t)(c0 + tr) * R + r0 + tc4 + 8) = o1.v;
}

// ---------------------------------------------------------------------------
// Layer-1 MFMA GEMM, no-LDS direct-register fragments, 1-deep register
// double-buffer (unchanged, verified).
// ---------------------------------------------------------------------------
__global__ __launch_bounds__(256) void k_l1(
    const unsigned short* __restrict__ docB, const unsigned short* __restrict__ segB,
    const unsigned short* __restrict__ W1T_bf, const float* __restrict__ b1,
    unsigned short* __restrict__ XdocB, unsigned short* __restrict__ XsegB)
{
    int mb = blockIdx.x;
    int n0 = blockIdx.y * 128;
    int t = threadIdx.x, w = t >> 6, l = t & 63;
    int lm = l & 15, kh = l >> 4;
    bool isdoc = (mb < 32);
    int m0 = isdoc ? mb * 64 : (mb - 32) * 64;
    const unsigned short* A = isdoc ? docB : segB;
    int koff = isdoc ? 0 : 768;
    unsigned short* C = isdoc ? XdocB : XsegB;

    const unsigned short* gA = A + (size_t)(m0 + lm) * 768 + kh * 8;
    const unsigned short* gB = W1T_bf + (size_t)(n0 + w * 32 + lm) * 1536 + koff + kh * 8;

    f32x4 acc[4][2];
    #pragma unroll
    for (int mt = 0; mt < 4; ++mt)
        #pragma unroll
        for (int nt = 0; nt < 2; ++nt) acc[mt][nt] = (f32x4){0.f, 0.f, 0.f, 0.f};

    bf16x8 aA[4], aB[4], bA[2], bB[2];
    #pragma unroll
    for (int mt = 0; mt < 4; ++mt) aA[mt] = *(const bf16x8*)(gA + (size_t)mt * 16 * 768);
    #pragma unroll
    for (int nt = 0; nt < 2; ++nt) bA[nt] = *(const bf16x8*)(gB + (size_t)nt * 16 * 1536);

    for (int kt = 0; kt < 12; ++kt) {
        int ko1 = kt * 64 + 32;
        #pragma unroll
        for (int mt = 0; mt < 4; ++mt) aB[mt] = *(const bf16x8*)(gA + (size_t)mt * 16 * 768 + ko1);
        #pragma unroll
        for (int nt = 0; nt < 2; ++nt) bB[nt] = *(const bf16x8*)(gB + (size_t)nt * 16 * 1536 + ko1);
        #pragma unroll
        for (int mt = 0; mt < 4; ++mt)
            #pragma unroll
            for (int nt = 0; nt < 2; ++nt)
                acc[mt][nt] = __builtin_amdgcn_mfma_f32_16x16x32_bf16(
                    aA[mt], bA[nt], acc[mt][nt], 0, 0, 0);
        if (kt < 11) {
            int ko2 = kt * 64 + 64;
            #pragma unroll
            for (int mt = 0; mt < 4; ++mt) aA[mt] = *(const bf16x8*)(gA + (size_t)mt * 16 * 768 + ko2);
            #pragma unroll
            for (int nt = 0; nt < 2; ++nt) bA[nt] = *(const bf16x8*)(gB + (size_t)nt * 16 * 1536 + ko2);
        }
        #pragma unroll
        for (int mt = 0; mt < 4; ++mt)
            #pragma unroll
            for (int nt = 0; nt < 2; ++nt)
                acc[mt][nt] = __builtin_amdgcn_mfma_f32_16x16x32_bf16(
                    aB[mt], bB[nt], acc[mt][nt], 0, 0, 0);
    }
    #pragma unroll
    for (int nt = 0; nt < 2; ++nt) {
        int n = n0 + w * 32 + nt * 16 + lm;
        float bv = isdoc ? 0.f : b1[n];
        #pragma unroll
        for (int mt = 0; mt < 4; ++mt)
            #pragma unroll
            for (int j = 0; j < 4; ++j) {
                int row = m0 + mt * 16 + kh * 4 + j;
                C[(size_t)row * 768 + n] = f2bf(acc[mt][nt][j] + bv);
            }
    }
}

// ---------------------------------------------------------------------------
// Fused layer-2+3 MFMA: block = (b,s). M=64, N=384, K=768, BK=64.
// Full-kt-deep prefetch: at top of kt, issue Xdoc[kt+1] AND all 12 W2T
// B-fragments for kt+1 (consumed a full kt later, ~1500 cyc — covers L2 and
// HBM-cold latency). Two named register sets, 2-step rolled loop (icache).
// ---------------------------------------------------------------------------
__global__ __launch_bounds__(256, 2) void k_fused_mfma(
    const unsigned short* __restrict__ XdocB, const unsigned short* __restrict__ XsegB,
    const unsigned short* __restrict__ W2T_bf,
    const float* __restrict__ b2, const float* __restrict__ W3, const float* __restrict__ b3,
    const int* __restrict__ nd, const int* __restrict__ ns,
    float* __restrict__ out_pred, float* __restrict__ predv)
{
    __shared__ unsigned short sA0[64 * 64];   // 8KB, swizzled rows of 128B
    __shared__ unsigned short sA1[64 * 64];   // 8KB
    __shared__ float sXseg[768];              // 3KB
    __shared__ float sRed[64][4];             // 1KB

    int bs = blockIdx.x;
    int b = bs >> 4;
    int t = threadIdx.x, w = t >> 6, l = t & 63;
    int lm = l & 15, kh = l >> 4, sw2 = (lm & 7) << 4;

    for (int i = t; i < 768; i += 256) sXseg[i] = bf2f(XsegB[(size_t)bs * 768 + i]);

    const int ndb = nd[b];
    const float segscale = (ns[b] > 10) ? 1.0f : 100.0f;
    const float b3v = b3[0];

    f32x4 acc[4][6];
    #pragma unroll
    for (int mt = 0; mt < 4; ++mt)
        #pragma unroll
        for (int nt = 0; nt < 6; ++nt) acc[mt][nt] = (f32x4){0.f, 0.f, 0.f, 0.f};

    int ar = t >> 2, ak = (t & 3) * 16;        // h1 staging: row 0..63, k-base
    int asw = (ar & 7) << 4;
    const char* gXd = (const char*)XdocB + (size_t)(b * 64 + ar) * 1536;
    const unsigned short* gW2w = W2T_bf + (size_t)(w * 96 + lm) * 768 + kh * 8;

    union u128 { uint4 v; unsigned short u[8]; };

    // Two named B register sets (12 frags each = one full kt: kk0 in [0..5],
    // kk1 in [6..11]). All indexing compile-time (rule #20).
    bf16x8 bA_[12], bB_[12];
    #pragma unroll
    for (int j = 0; j < 12; ++j) {
        int nt = j % 6, kk = j / 6;
        bA_[j] = *(const bf16x8*)(gW2w + (size_t)nt * 16 * 768 + kk * 32);
    }

    // prologue: load + gelu + write kt=0 into sA0
    {
        u128 xc0, xc1;
        xc0.v = *(const uint4*)(gXd + ak * 2);
        xc1.v = *(const uint4*)(gXd + ak * 2 + 16);
        __syncthreads();          // sXseg ready
        u128 o0, o1;
        #pragma unroll
        for (int i = 0; i < 8; ++i)
            o0.u[i] = f2bf(gelu_fast(bf2f(xc0.u[i]) + sXseg[ak + i]));
        #pragma unroll
        for (int i = 0; i < 8; ++i)
            o1.u[i] = f2bf(gelu_fast(bf2f(xc1.u[i]) + sXseg[ak + 8 + i]));
        *(uint4*)((char*)sA0 + ar * 128 + ((ak * 2) ^ asw)) = o0.v;
        *(uint4*)((char*)sA0 + ar * 128 + ((ak * 2 + 16) ^ asw)) = o1.v;
    }

    // BODY: one kt step. BCUR holds this kt's 12 B frags; BNXT is filled with
    // kt+1's frags right after the barrier (full-kt prefetch distance).
    #define KT_BODY(KT, BCUR, BNXT, CBUF, NBUF)                                 \
    {                                                                           \
        __syncthreads();      /* CBUF writes visible; prior NBUF reads done */  \
        u128 xn0, xn1;                                                          \
        if ((KT) < 11) {                                                        \
            xn0.v = *(const uint4*)(gXd + ((KT) + 1) * 128 + ak * 2);           \
            xn1.v = *(const uint4*)(gXd + ((KT) + 1) * 128 + ak * 2 + 16);      \
            _Pragma("unroll")                                                   \
            for (int j_ = 0; j_ < 12; ++j_) {                                   \
                int nt_ = j_ % 6, kk_ = j_ / 6;                                 \
                BNXT[j_] = *(const bf16x8*)(gW2w + (size_t)nt_ * 16 * 768       \
                                            + ((KT) + 1) * 64 + kk_ * 32);      \
            }                                                                   \
        }                                                                       \
        {   /* kk = 0 */                                                        \
            int kb = (kh * 16) ^ sw2;                                           \
            bf16x8 a_[4];                                                       \
            _Pragma("unroll")                                                   \
            for (int mt = 0; mt < 4; ++mt)                                      \
                a_[mt] = *(const bf16x8*)((const char*)(CBUF)                   \
                                          + (mt * 16 + lm) * 128 + kb);         \
            _Pragma("unroll")                                                   \
            for (int mt = 0; mt < 4; ++mt)                                      \
                _Pragma("unroll")                                               \
                for (int nt = 0; nt < 6; ++nt)                                  \
                    acc[mt][nt] = __builtin_amdgcn_mfma_f32_16x16x32_bf16(      \
                        a_[mt], BCUR[nt], acc[mt][nt], 0, 0, 0);                \
        }                                                                       \
        {   /* kk = 1 */                                                        \
            int kb = (64 + kh * 16) ^ sw2;                                      \
            bf16x8 a_[4];                                                       \
            _Pragma("unroll")                                                   \
            for (int mt = 0; mt < 4; ++mt)                                      \
                a_[mt] = *(const bf16x8*)((const char*)(CBUF)                   \
                                          + (mt * 16 + lm) * 128 + kb);         \
            _Pragma("unroll")                                                   \
            for (int mt = 0; mt < 4; ++mt)                                      \
                _Pragma("unroll")                                               \
                for (int nt = 0; nt < 6; ++nt)                                  \
                    acc[mt][nt] = __builtin_amdgcn_mfma_f32_16x16x32_bf16(      \
                        a_[mt], BCUR[6 + nt], acc[mt][nt], 0, 0, 0);            \
        }                                                                       \
        if ((KT) < 11) {  /* write-late: gelu + LDS store for kt+1 */           \
            u128 o0, o1;                                                        \
            _Pragma("unroll")                                                   \
            for (int i_ = 0; i_ < 8; ++i_)                                      \
                o0.u[i_] = f2bf(gelu_fast(bf2f(xn0.u[i_])                       \
                                 + sXseg[((KT) + 1) * 64 + ak + i_]));          \
            _Pragma("unroll")                                                   \
            for (int i_ = 0; i_ < 8; ++i_)                                      \
                o1.u[i_] = f2bf(gelu_fast(bf2f(xn1.u[i_])                       \
                                 + sXseg[((KT) + 1) * 64 + ak + 8 + i_]));      \
            *(uint4*)((char*)(NBUF) + ar * 128 + ((ak * 2) ^ asw)) = o0.v;      \
            *(uint4*)((char*)(NBUF) + ar * 128 + ((ak * 2 + 16) ^ asw)) = o1.v; \
        }                                                                       \
    }

    for (int kt2 = 0; kt2 < 12; kt2 += 2) {
        KT_BODY(kt2,     bA_, bB_, sA0, sA1);
        KT_BODY(kt2 + 1, bB_, bA_, sA1, sA0);
    }
    #undef KT_BODY

    // epilogue: h3[row] = sum_n gelu(h2+b2[n])*W3[n]; sigmoid; masked max
    float b2v[6], w3v[6];
    #pragma unroll
    for (int nt = 0; nt < 6; ++nt) {
        int n = w * 96 + nt * 16 + lm;
        b2v[nt] = b2[n]; w3v[nt] = W3[n];
    }
    #pragma unroll
    for (int mt = 0; mt < 4; ++mt) {
        #pragma unroll
        for (int j = 0; j < 4; ++j) {
            float s = 0.f;
            #pragma unroll
            for (int nt = 0; nt < 6; ++nt)
                s += gelu_fast(acc[mt][nt][j] + b2v[nt]) * w3v[nt];
            s += __shfl_xor(s, 1); s += __shfl_xor(s, 2);
            s += __shfl_xor(s, 4); s += __shfl_xor(s, 8);
            if (lm == 0) sRed[mt * 16 + kh * 4 + j][w] = s;
        }
    }
    __syncthreads();
    if (w == 0) {
        float h3 = sRed[l][0] + sRed[l][1] + sRed[l][2] + sRed[l][3] + b3v;
        float sig = sigmoid_fast(h3);
        float val = (l < ndb) ? sig : 0.f;
        #pragma unroll
        for (int off = 32; off > 0; off >>= 1) val = fmaxf(val, __shfl_xor(val, off));
        if (l == 0) {
            float pv = segscale * val;
            out_pred[bs] = pv;
            predv[bs] = pv;
        }
    }
}

// ---------------------------------------------------------------------------
// k_post: blocks [0,32) = cos prior per b; blocks [32,64) = corr prior per b.
// ---------------------------------------------------------------------------
__global__ __launch_bounds__(256) void k_post(
    const unsigned short* __restrict__ docB, const unsigned short* __restrict__ segB,
    const float* __restrict__ seg,
    const float* __restrict__ dscale, const float* __restrict__ sscale,
    const float* __restrict__ smean, const float* __restrict__ cscale,
    const int* __restrict__ nd, const int* __restrict__ ns,
    const float* __restrict__ predv,
    float* __restrict__ diffs, float* __restrict__ corrb)
{
    __shared__ float sZ[16][772];
    __shared__ float sRedC[16][4];
    __shared__ float sPred[16];
    __shared__ float wsum[4];
    int blk = blockIdx.x;
    int t = threadIdx.x;

    if (blk < 32) {
        int b = blk;
        int w = t >> 6, l = t & 63;
        int lm = l & 15, kh = l >> 4;
        const unsigned short* gS = segB + (size_t)(b * 16 + lm) * 768 + kh * 8;
        const unsigned short* gD = docB + (size_t)(b * 64 + w * 16 + lm) * 768 + kh * 8;
        f32x4 acc = (f32x4){0.f, 0.f, 0.f, 0.f};
        for (int kt = 0; kt < 24; ++kt) {
            bf16x8 a = *(const bf16x8*)(gS + kt * 32);
            bf16x8 bb = *(const bf16x8*)(gD + kt * 32);
            acc = __builtin_amdgcn_mfma_f32_16x16x32_bf16(a, bb, acc, 0, 0, 0);
        }
        int ndb = nd[b];
        int d = w * 16 + lm;
        float dsc = dscale[b * 64 + d];
        #pragma unroll
        for (int j = 0; j < 4; ++j) {
            int s = kh * 4 + j;
            float cosv = acc[j] * sscale[b * 16 + s] * dsc;
            float sim = (d < ndb) ? (1.0f - cosv) * 0.5f : 0.f;
            sim = fmaxf(sim, __shfl_xor(sim, 1));
            sim = fmaxf(sim, __shfl_xor(sim, 2));
            sim = fmaxf(sim, __shfl_xor(sim, 4));
            sim = fmaxf(sim, __shfl_xor(sim, 8));
            if (lm == 0) sRedC[s][w] = sim;
        }
        __syncthreads();
        if (t < 16) {
            float dc = fmaxf(fmaxf(sRedC[t][0], sRedC[t][1]),
                             fmaxf(sRedC[t][2], sRedC[t][3]));
            float diff = fabsf(dc - predv[b * 16 + t]);
            diffs[b * 16 + t] = (t < ns[b]) ? diff : 0.f;
        }
        return;
    }

    // ---- corr prior ----
    int b = blk - 32;
    if (t < 16) sPred[t] = predv[b * 16 + t];
    for (int i = t; i < 16 * 768; i += 256) {
        int s = i / 768; int e = i - s * 768;
        sZ[s][e] = (seg[((size_t)b * 16 + s) * 768 + e] - smean[b * 16 + s]) * cscale[b * 16 + s];
    }
    __syncthreads();
    int s = t >> 4, tt = t & 15;
    const float4* z1 = (const float4*)&sZ[s][0];
    const float4* z2 = (const float4*)&sZ[tt][0];
    float dot = 0.f;
    #pragma unroll 4
    for (int e = 0; e < 192; ++e) {
        float4 a = z1[e], c = z2[e];
        dot += a.x * c.x + a.y * c.y + a.z * c.z + a.w * c.w;
    }
    float R = 0.5f * (1.0f + dot);
    int nsb = ns[b];
    float ps = sPred[s], pt = sPred[tt];
    float t1 = (1.f - ps) * (1.f - pt), t2 = ps * pt;
    float term = (s < nsb && tt < nsb) ? fabsf(t1 - R) * fabsf(t2 - R) : 0.f;
    #pragma unroll
    for (int off = 32; off > 0; off >>= 1) term += __shfl_down(term, off);
    int lane = t & 63, w = t >> 6;
    if (lane == 0) wsum[w] = term;
    __syncthreads();
    if (t == 0) corrb[b] = (wsum[0] + wsum[1] + wsum[2] + wsum[3]) / (float)nsb;
}

// ---------------------------------------------------------------------------
// Finalize (unchanged layout)
// ---------------------------------------------------------------------------
__global__ __launch_bounds__(256) void k_final(
    const float* __restrict__ tagg, const float* __restrict__ tis,
    const int* __restrict__ ns, const float* __restrict__ diffs,
    const float* __restrict__ corrb, float* __restrict__ out)
{
    int t = threadIdx.x;
    if (t < 32) out[t] = tagg[t];
    out[32 + t] = tis[t];
    out[32 + 256 + t] = tis[256 + t];
    if (t < 32) out[1056 + t] = (float)ns[t];
    float l1 = 0.f, l2 = 0.f;
    if (t < 32) {
        float sb = 0.f;
        #pragma unroll
        for (int s2 = 0; s2 < 16; ++s2) sb += diffs[t * 16 + s2];
        l1 = sb / (float)ns[t];
        l2 = corrb[t];
    }
    #pragma unroll
    for (int off = 16; off > 0; off >>= 1) {
        l1 += __shfl_down(l1, off);
        l2 += __shfl_down(l2, off);
    }
    if (t == 0) { out[1088] = l1 * (1.0f / 32.0f); out[1089] = l2 * (1.0f / 32.0f); }
}

// ---------------------------------------------------------------------------
extern "C" void kernel_launch(void* const* d_in, const int* in_sizes, int n_in,
                              void* d_out, int out_size, void* d_ws, size_t ws_size,
                              hipStream_t stream)
{
    const float* doc  = (const float*)d_in[0];
    const float* seg  = (const float*)d_in[1];
    const int*   nd   = (const int*)d_in[2];
    const int*   ns   = (const int*)d_in[3];
    const float* tagg = (const float*)d_in[4];
    const float* tis  = (const float*)d_in[5];
    const float* W1   = (const float*)d_in[6];   // [1536][768]
    const float* b1   = (const float*)d_in[7];
    const float* W2   = (const float*)d_in[8];   // [768][384]
    const float* b2   = (const float*)d_in[9];
    const float* W3   = (const float*)d_in[10];
    const float* b3   = (const float*)d_in[11];
    float* out = (float*)d_out;

    float* fws      = (float*)d_ws;
    float* dscale   = fws;                 // 2048
    float* sscale   = dscale + 2048;       // 512
    float* smean    = sscale + 512;        // 512
    float* cscale   = smean + 512;         // 512
    float* predv    = cscale + 512;        // 512
    float* diffs    = predv + 512;         // 512
    float* corrb    = diffs + 512;         // 32
    unsigned short* docB  = (unsigned short*)(corrb + 32);
    unsigned short* segB  = docB + (size_t)2048 * 768;
    unsigned short* W1T   = segB + (size_t)512 * 768;     // [768][1536]
    unsigned short* W2T   = W1T + (size_t)768 * 1536;     // [384][768]
    unsigned short* XdocB = W2T + (size_t)384 * 768;      // [2048][768]
    unsigned short* XsegB = XdocB + (size_t)2048 * 768;   // [512][768]

    k_prep<<<1000, 256, 0, stream>>>(doc, seg, W1, W2, dscale, sscale, smean,
                                     cscale, docB, segB, W1T, W2T);
    k_l1<<<dim3(40, 6), 256, 0, stream>>>(docB, segB, W1T, b1, XdocB, XsegB);
    k_fused_mfma<<<512, 256, 0, stream>>>(XdocB, XsegB, W2T, b2, W3, b3, nd, ns,
                                          out + 544, predv);
    k_post<<<64, 256, 0, stream>>>(docB, segB, seg, dscale, sscale, smean,
                                   cscale, nd, ns, predv, diffs, corrb);
    k_final<<<1, 256, 0, stream>>>(tagg, tis, ns, diffs, corrb, out);
}

// Round 8
// 83.978 us; speedup vs baseline: 1.1607x; 1.1607x over previous
//
#include <hip/hip_runtime.h>
#include <hip/hip_bf16.h>
#include <math.h>

// Problem constants: B=32, S=16, D=64, E=768
#define EPSF 1e-12f

typedef short bf16x8 __attribute__((ext_vector_type(8)));
typedef float f32x4  __attribute__((ext_vector_type(4)));

// tanh-approx GELU via native exp2/rcp: max abs err ~3e-4 vs exact erf-gelu.
__device__ __forceinline__ float gelu_fast(float x) {
    float x2 = x * x;
    float z = -2.3021184f * x * fmaf(0.044715f, x2, 1.0f);
    float u = __builtin_amdgcn_exp2f(z);
    return x * __builtin_amdgcn_rcpf(1.0f + u);
}
__device__ __forceinline__ float sigmoid_fast(float x) {
    float u = __builtin_amdgcn_exp2f(-1.44269504f * x);
    return __builtin_amdgcn_rcpf(1.0f + u);
}
__device__ __forceinline__ float bf2f(unsigned short u) {
    return __uint_as_float(((unsigned int)u) << 16);
}
__device__ __forceinline__ unsigned short f2bf(float f) {
    unsigned int u = __float_as_uint(f);
    u += 0x7FFFu + ((u >> 16) & 1u);     // RNE
    return (unsigned short)(u >> 16);
}

// ---------------------------------------------------------------------------
// k_prep: [0,640) norms+bf16-cvt (4 rows/block); [640,1000) W1/W2 transpose;
// block 1000: passthrough output copies (tagg, tis, ns).
// ---------------------------------------------------------------------------
__global__ __launch_bounds__(256) void k_prep(
    const float* __restrict__ doc, const float* __restrict__ seg,
    const float* __restrict__ W1, const float* __restrict__ W2,
    const float* __restrict__ tagg, const float* __restrict__ tis,
    const int* __restrict__ ns,
    float* __restrict__ dscale, float* __restrict__ sscale,
    float* __restrict__ smean, float* __restrict__ cscale,
    unsigned short* __restrict__ docB, unsigned short* __restrict__ segB,
    unsigned short* __restrict__ W1T, unsigned short* __restrict__ W2T,
    float* __restrict__ out)
{
    __shared__ float sT[64][65];
    int blk = blockIdx.x;
    int t = threadIdx.x;
    if (blk == 1000) {
        if (t < 32) out[t] = tagg[t];
        out[32 + t] = tis[t];
        out[32 + 256 + t] = tis[256 + t];
        if (t < 32) out[1056 + t] = (float)ns[t];
        return;
    }
    if (blk < 640) {
        int row = blk * 4 + (t >> 6);
        int lane = t & 63;
        const float* src = (row < 2048) ? (doc + (size_t)row * 768)
                                        : (seg + (size_t)(row - 2048) * 768);
        unsigned short* dst = (row < 2048) ? (docB + (size_t)row * 768)
                                           : (segB + (size_t)(row - 2048) * 768);
        float ss = 0.f, sm = 0.f;
        float xv[12];
        #pragma unroll
        for (int i = 0; i < 12; ++i) {
            float x = src[lane + 64 * i];
            xv[i] = x;
            ss += x * x; sm += x;
        }
        #pragma unroll
        for (int i = 0; i < 12; ++i) dst[lane + 64 * i] = f2bf(xv[i]);
        #pragma unroll
        for (int off = 32; off > 0; off >>= 1) {
            ss += __shfl_down(ss, off);
            sm += __shfl_down(sm, off);
        }
        if (lane == 0) {
            if (row < 2048) {
                dscale[row] = rsqrtf(fmaxf(ss, EPSF));
            } else {
                int r = row - 2048;
                sscale[r] = rsqrtf(fmaxf(ss, EPSF));
                float mean = sm * (1.0f / 768.0f);
                smean[r] = mean;
                cscale[r] = rsqrtf(fmaxf(ss - sm * mean, EPSF));
            }
        }
        return;
    }
    // transpose tiles
    int tt = blk - 640;
    const float* in; unsigned short* out2; int R, C, bx, by;
    if (tt < 288) { in = W1; out2 = W1T; R = 1536; C = 768; bx = tt % 12; by = tt / 12; }
    else { tt -= 288; in = W2; out2 = W2T; R = 768; C = 384; bx = tt % 6; by = tt / 6; }
    int c0 = bx * 64, r0 = by * 64;
    int tr = t >> 2, tc4 = (t & 3) * 16;
    #pragma unroll
    for (int i = 0; i < 4; ++i) {
        float4 v = *(const float4*)(in + (size_t)(r0 + tr) * C + c0 + tc4 + i * 4);
        sT[tr][tc4 + i * 4 + 0] = v.x; sT[tr][tc4 + i * 4 + 1] = v.y;
        sT[tr][tc4 + i * 4 + 2] = v.z; sT[tr][tc4 + i * 4 + 3] = v.w;
    }
    __syncthreads();
    union { uint4 v; unsigned short u[8]; } o0, o1;
    #pragma unroll
    for (int i = 0; i < 8; ++i) o0.u[i] = f2bf(sT[tc4 + i][tr]);
    #pragma unroll
    for (int i = 0; i < 8; ++i) o1.u[i] = f2bf(sT[tc4 + 8 + i][tr]);
    *(uint4*)(out2 + (size_t)(c0 + tr) * R + r0 + tc4) = o0.v;
    *(uint4*)(out2 + (size_t)(c0 + tr) * R + r0 + tc4 + 8) = o1.v;
}

// ---------------------------------------------------------------------------
// Layer-1 MFMA GEMM, no-LDS direct-register fragments, 1-deep register
// double-buffer (unchanged, verified round 6).
// ---------------------------------------------------------------------------
__global__ __launch_bounds__(256) void k_l1(
    const unsigned short* __restrict__ docB, const unsigned short* __restrict__ segB,
    const unsigned short* __restrict__ W1T_bf, const float* __restrict__ b1,
    unsigned short* __restrict__ XdocB, unsigned short* __restrict__ XsegB)
{
    int mb = blockIdx.x;
    int n0 = blockIdx.y * 128;
    int t = threadIdx.x, w = t >> 6, l = t & 63;
    int lm = l & 15, kh = l >> 4;
    bool isdoc = (mb < 32);
    int m0 = isdoc ? mb * 64 : (mb - 32) * 64;
    const unsigned short* A = isdoc ? docB : segB;
    int koff = isdoc ? 0 : 768;
    unsigned short* C = isdoc ? XdocB : XsegB;

    const unsigned short* gA = A + (size_t)(m0 + lm) * 768 + kh * 8;
    const unsigned short* gB = W1T_bf + (size_t)(n0 + w * 32 + lm) * 1536 + koff + kh * 8;

    f32x4 acc[4][2];
    #pragma unroll
    for (int mt = 0; mt < 4; ++mt)
        #pragma unroll
        for (int nt = 0; nt < 2; ++nt) acc[mt][nt] = (f32x4){0.f, 0.f, 0.f, 0.f};

    bf16x8 aA[4], aB[4], bA[2], bB[2];
    #pragma unroll
    for (int mt = 0; mt < 4; ++mt) aA[mt] = *(const bf16x8*)(gA + (size_t)mt * 16 * 768);
    #pragma unroll
    for (int nt = 0; nt < 2; ++nt) bA[nt] = *(const bf16x8*)(gB + (size_t)nt * 16 * 1536);

    for (int kt = 0; kt < 12; ++kt) {
        int ko1 = kt * 64 + 32;
        #pragma unroll
        for (int mt = 0; mt < 4; ++mt) aB[mt] = *(const bf16x8*)(gA + (size_t)mt * 16 * 768 + ko1);
        #pragma unroll
        for (int nt = 0; nt < 2; ++nt) bB[nt] = *(const bf16x8*)(gB + (size_t)nt * 16 * 1536 + ko1);
        #pragma unroll
        for (int mt = 0; mt < 4; ++mt)
            #pragma unroll
            for (int nt = 0; nt < 2; ++nt)
                acc[mt][nt] = __builtin_amdgcn_mfma_f32_16x16x32_bf16(
                    aA[mt], bA[nt], acc[mt][nt], 0, 0, 0);
        if (kt < 11) {
            int ko2 = kt * 64 + 64;
            #pragma unroll
            for (int mt = 0; mt < 4; ++mt) aA[mt] = *(const bf16x8*)(gA + (size_t)mt * 16 * 768 + ko2);
            #pragma unroll
            for (int nt = 0; nt < 2; ++nt) bA[nt] = *(const bf16x8*)(gB + (size_t)nt * 16 * 1536 + ko2);
        }
        #pragma unroll
        for (int mt = 0; mt < 4; ++mt)
            #pragma unroll
            for (int nt = 0; nt < 2; ++nt)
                acc[mt][nt] = __builtin_amdgcn_mfma_f32_16x16x32_bf16(
                    aB[mt], bB[nt], acc[mt][nt], 0, 0, 0);
    }
    #pragma unroll
    for (int nt = 0; nt < 2; ++nt) {
        int n = n0 + w * 32 + nt * 16 + lm;
        float bv = isdoc ? 0.f : b1[n];
        #pragma unroll
        for (int mt = 0; mt < 4; ++mt)
            #pragma unroll
            for (int j = 0; j < 4; ++j) {
                int row = m0 + mt * 16 + kh * 4 + j;
                C[(size_t)row * 768 + n] = f2bf(acc[mt][nt][j] + bv);
            }
    }
}

// ---------------------------------------------------------------------------
// Fused layer-2+3 MFMA (round-6 verified body) + rider blocks:
// blocks [0,512): pred per (b,s); [512,544): cos dc per b; [544,576): corr R
// per b (MFMA z@z^T). Riders are pred-independent; k_final combines.
// ---------------------------------------------------------------------------
__global__ __launch_bounds__(256, 2) void k_fused_mfma(
    const unsigned short* __restrict__ XdocB, const unsigned short* __restrict__ XsegB,
    const unsigned short* __restrict__ W2T_bf,
    const float* __restrict__ b2, const float* __restrict__ W3, const float* __restrict__ b3,
    const int* __restrict__ nd, const int* __restrict__ ns,
    const unsigned short* __restrict__ docB, const unsigned short* __restrict__ segB,
    const float* __restrict__ seg,
    const float* __restrict__ dscale, const float* __restrict__ sscale,
    const float* __restrict__ smean, const float* __restrict__ cscale,
    float* __restrict__ out_pred, float* __restrict__ predv,
    float* __restrict__ dcws, float* __restrict__ Rws)
{
    __shared__ union {
        struct {
            unsigned short sA0[64 * 64];   // 8KB, swizzled rows of 128B
            unsigned short sA1[64 * 64];   // 8KB
            float sXseg[768];              // 3KB
            float sRed[64][4];             // 1KB
        } p;
        struct { float sRedC[16][4]; } c;
        struct { unsigned short zb[16][776]; } r;   // ~24.8KB
    } U;

    int blk = blockIdx.x;
    int t = threadIdx.x, w = t >> 6, l = t & 63;
    int lm = l & 15, kh = l >> 4;

    if (blk >= 512) {
        if (blk < 544) {
            // ---- cos rider: dc[b][s] = max_d masked (1-cos)/2 ----
            int b = blk - 512;
            const unsigned short* gS = segB + (size_t)(b * 16 + lm) * 768 + kh * 8;
            const unsigned short* gD = docB + (size_t)(b * 64 + w * 16 + lm) * 768 + kh * 8;
            f32x4 acc = (f32x4){0.f, 0.f, 0.f, 0.f};
            for (int kt = 0; kt < 24; ++kt) {
                bf16x8 a = *(const bf16x8*)(gS + kt * 32);
                bf16x8 bb = *(const bf16x8*)(gD + kt * 32);
                acc = __builtin_amdgcn_mfma_f32_16x16x32_bf16(a, bb, acc, 0, 0, 0);
            }
            int ndb = nd[b];
            int d = w * 16 + lm;
            float dsc = dscale[b * 64 + d];
            #pragma unroll
            for (int j = 0; j < 4; ++j) {
                int s = kh * 4 + j;
                float cosv = acc[j] * sscale[b * 16 + s] * dsc;
                float sim = (d < ndb) ? (1.0f - cosv) * 0.5f : 0.f;
                sim = fmaxf(sim, __shfl_xor(sim, 1));
                sim = fmaxf(sim, __shfl_xor(sim, 2));
                sim = fmaxf(sim, __shfl_xor(sim, 4));
                sim = fmaxf(sim, __shfl_xor(sim, 8));
                if (lm == 0) U.c.sRedC[s][w] = sim;
            }
            __syncthreads();
            if (t < 16) {
                float dc = fmaxf(fmaxf(U.c.sRedC[t][0], U.c.sRedC[t][1]),
                                 fmaxf(U.c.sRedC[t][2], U.c.sRedC[t][3]));
                dcws[b * 16 + t] = dc;
            }
        } else {
            // ---- corr rider: R[b][s][t] = (1 + z_s . z_t)/2 via MFMA ----
            int b = blk - 544;
            for (int i = t; i < 16 * 768; i += 256) {
                int s = i / 768; int e = i - s * 768;
                U.r.zb[s][e] = f2bf((seg[((size_t)b * 16 + s) * 768 + e]
                                     - smean[b * 16 + s]) * cscale[b * 16 + s]);
            }
            __syncthreads();
            if (w == 0) {
                f32x4 acc = (f32x4){0.f, 0.f, 0.f, 0.f};
                #pragma unroll
                for (int kt = 0; kt < 24; ++kt) {
                    bf16x8 z = *(const bf16x8*)&U.r.zb[lm][kt * 32 + kh * 8];
                    acc = __builtin_amdgcn_mfma_f32_16x16x32_bf16(z, z, acc, 0, 0, 0);
                }
                #pragma unroll
                for (int j = 0; j < 4; ++j) {
                    int row = kh * 4 + j;
                    Rws[b * 256 + row * 16 + lm] = 0.5f * (1.0f + acc[j]);
                }
            }
        }
        return;
    }

    // ---------------- pred path (round-6 verified) ----------------
    int bs = blk;
    int b = bs >> 4;
    int sw2 = (lm & 7) << 4;

    for (int i = t; i < 768; i += 256) U.p.sXseg[i] = bf2f(XsegB[(size_t)bs * 768 + i]);

    const int ndb = nd[b];
    const float segscale = (ns[b] > 10) ? 1.0f : 100.0f;
    const float b3v = b3[0];

    f32x4 acc[4][6];
    #pragma unroll
    for (int mt = 0; mt < 4; ++mt)
        #pragma unroll
        for (int nt = 0; nt < 6; ++nt) acc[mt][nt] = (f32x4){0.f, 0.f, 0.f, 0.f};

    int ar = t >> 2, ak = (t & 3) * 16;        // h1 staging: row 0..63, k-base
    int asw = (ar & 7) << 4;
    const char* gXd = (const char*)XdocB + (size_t)(b * 64 + ar) * 1536;
    const unsigned short* gW2w = W2T_bf + (size_t)(w * 96 + lm) * 768 + kh * 8;

    union u128 { uint4 v; unsigned short u[8]; };

    // B register double-buffer: bbA = next kk=0 fragments; bbB = next kk=1.
    bf16x8 bbA[6], bbB[6];
    #pragma unroll
    for (int nt = 0; nt < 6; ++nt)
        bbA[nt] = *(const bf16x8*)(gW2w + (size_t)nt * 16 * 768);

    // prologue: load + gelu + write kt=0 into sA0
    {
        u128 xc0, xc1;
        xc0.v = *(const uint4*)(gXd + ak * 2);
        xc1.v = *(const uint4*)(gXd + ak * 2 + 16);
        __syncthreads();          // sXseg ready
        u128 o0, o1;
        #pragma unroll
        for (int i = 0; i < 8; ++i)
            o0.u[i] = f2bf(gelu_fast(bf2f(xc0.u[i]) + U.p.sXseg[ak + i]));
        #pragma unroll
        for (int i = 0; i < 8; ++i)
            o1.u[i] = f2bf(gelu_fast(bf2f(xc1.u[i]) + U.p.sXseg[ak + 8 + i]));
        *(uint4*)((char*)U.p.sA0 + ar * 128 + ((ak * 2) ^ asw)) = o0.v;
        *(uint4*)((char*)U.p.sA0 + ar * 128 + ((ak * 2 + 16) ^ asw)) = o1.v;
    }

    #pragma unroll
    for (int kt = 0; kt < 12; ++kt) {
        unsigned short* cbuf = (kt & 1) ? U.p.sA1 : U.p.sA0;
        unsigned short* nbuf = (kt & 1) ? U.p.sA0 : U.p.sA1;
        __syncthreads();      // cbuf writes visible; prior nbuf reads done
        // issue-early: next K-chunk's Xdoc load
        u128 xn0, xn1;
        if (kt < 11) {
            xn0.v = *(const uint4*)(gXd + (kt + 1) * 128 + ak * 2);
            xn1.v = *(const uint4*)(gXd + (kt + 1) * 128 + ak * 2 + 16);
        }
        // ---- kk = 0: prefetch bbB (this kt's kk=1), compute with bbA ----
        {
            #pragma unroll
            for (int nt = 0; nt < 6; ++nt)
                bbB[nt] = *(const bf16x8*)(gW2w + (size_t)nt * 16 * 768 + kt * 64 + 32);
            int kb = (kh * 16) ^ sw2;
            bf16x8 a[4];
            #pragma unroll
            for (int mt = 0; mt < 4; ++mt)
                a[mt] = *(const bf16x8*)((const char*)cbuf + (mt * 16 + lm) * 128 + kb);
            #pragma unroll
            for (int mt = 0; mt < 4; ++mt)
                #pragma unroll
                for (int nt = 0; nt < 6; ++nt)
                    acc[mt][nt] = __builtin_amdgcn_mfma_f32_16x16x32_bf16(
                        a[mt], bbA[nt], acc[mt][nt], 0, 0, 0);
        }
        // ---- kk = 1: prefetch bbA (next kt's kk=0), compute with bbB ----
        {
            if (kt < 11) {
                #pragma unroll
                for (int nt = 0; nt < 6; ++nt)
                    bbA[nt] = *(const bf16x8*)(gW2w + (size_t)nt * 16 * 768 + (kt + 1) * 64);
            }
            int kb = (64 + kh * 16) ^ sw2;
            bf16x8 a[4];
            #pragma unroll
            for (int mt = 0; mt < 4; ++mt)
                a[mt] = *(const bf16x8*)((const char*)cbuf + (mt * 16 + lm) * 128 + kb);
            #pragma unroll
            for (int mt = 0; mt < 4; ++mt)
                #pragma unroll
                for (int nt = 0; nt < 6; ++nt)
                    acc[mt][nt] = __builtin_amdgcn_mfma_f32_16x16x32_bf16(
                        a[mt], bbB[nt], acc[mt][nt], 0, 0, 0);
        }
        // write-late: gelu + LDS store for kt+1
        if (kt < 11) {
            u128 o0, o1;
            #pragma unroll
            for (int i = 0; i < 8; ++i)
                o0.u[i] = f2bf(gelu_fast(bf2f(xn0.u[i]) + U.p.sXseg[(kt + 1) * 64 + ak + i]));
            #pragma unroll
            for (int i = 0; i < 8; ++i)
                o1.u[i] = f2bf(gelu_fast(bf2f(xn1.u[i]) + U.p.sXseg[(kt + 1) * 64 + ak + 8 + i]));
            *(uint4*)((char*)nbuf + ar * 128 + ((ak * 2) ^ asw)) = o0.v;
            *(uint4*)((char*)nbuf + ar * 128 + ((ak * 2 + 16) ^ asw)) = o1.v;
        }
    }

    // epilogue: h3[row] = sum_n gelu(h2+b2[n])*W3[n]; sigmoid; masked max
    float b2v[6], w3v[6];
    #pragma unroll
    for (int nt = 0; nt < 6; ++nt) {
        int n = w * 96 + nt * 16 + lm;
        b2v[nt] = b2[n]; w3v[nt] = W3[n];
    }
    #pragma unroll
    for (int mt = 0; mt < 4; ++mt) {
        #pragma unroll
        for (int j = 0; j < 4; ++j) {
            float s = 0.f;
            #pragma unroll
            for (int nt = 0; nt < 6; ++nt)
                s += gelu_fast(acc[mt][nt][j] + b2v[nt]) * w3v[nt];
            s += __shfl_xor(s, 1); s += __shfl_xor(s, 2);
            s += __shfl_xor(s, 4); s += __shfl_xor(s, 8);
            if (lm == 0) U.p.sRed[mt * 16 + kh * 4 + j][w] = s;
        }
    }
    __syncthreads();
    if (w == 0) {
        float h3 = U.p.sRed[l][0] + U.p.sRed[l][1] + U.p.sRed[l][2] + U.p.sRed[l][3] + b3v;
        float sig = sigmoid_fast(h3);
        float val = (l < ndb) ? sig : 0.f;
        #pragma unroll
        for (int off = 32; off > 0; off >>= 1) val = fmaxf(val, __shfl_xor(val, off));
        if (l == 0) {
            float pv = segscale * val;
            out_pred[bs] = pv;
            predv[bs] = pv;
        }
    }
}

// ---------------------------------------------------------------------------
// k_final: combine riders with pred. cos_prior from dc & pred; corr_prior
// from R & pred. One block, 256 threads.
// ---------------------------------------------------------------------------
__global__ __launch_bounds__(256) void k_final(
    const int* __restrict__ ns, const float* __restrict__ dcws,
    const float* __restrict__ Rws, const float* __restrict__ predv,
    float* __restrict__ out)
{
    __shared__ float sl1[32], sl2[32];
    int t = threadIdx.x;
    if (t < 32) {
        int nsb = ns[t];
        float sb = 0.f;
        #pragma unroll
        for (int s = 0; s < 16; ++s) {
            float d = fabsf(dcws[t * 16 + s] - predv[t * 16 + s]);
            sb += (s < nsb) ? d : 0.f;
        }
        sl1[t] = sb / (float)nsb;
    }
    {
        int b = t >> 3, c = t & 7;
        int nsb = ns[b];
        float sum = 0.f;
        #pragma unroll
        for (int k = 0; k < 32; ++k) {
            int idx = c * 32 + k;
            int s = idx >> 4, tt = idx & 15;
            float R = Rws[b * 256 + idx];
            float ps = predv[b * 16 + s], pt = predv[b * 16 + tt];
            float t1 = (1.f - ps) * (1.f - pt), t2 = ps * pt;
            float term = fabsf(t1 - R) * fabsf(t2 - R);
            sum += (s < nsb && tt < nsb) ? term : 0.f;
        }
        sum += __shfl_xor(sum, 1);
        sum += __shfl_xor(sum, 2);
        sum += __shfl_xor(sum, 4);
        if (c == 0) sl2[b] = sum / (float)nsb;
    }
    __syncthreads();
    if (t == 0) {
        float a = 0.f, bsum = 0.f;
        #pragma unroll
        for (int i = 0; i < 32; ++i) { a += sl1[i]; bsum += sl2[i]; }
        out[1088] = a * (1.0f / 32.0f);
        out[1089] = bsum * (1.0f / 32.0f);
    }
}

// ---------------------------------------------------------------------------
extern "C" void kernel_launch(void* const* d_in, const int* in_sizes, int n_in,
                              void* d_out, int out_size, void* d_ws, size_t ws_size,
                              hipStream_t stream)
{
    const float* doc  = (const float*)d_in[0];
    const float* seg  = (const float*)d_in[1];
    const int*   nd   = (const int*)d_in[2];
    const int*   ns   = (const int*)d_in[3];
    const float* tagg = (const float*)d_in[4];
    const float* tis  = (const float*)d_in[5];
    const float* W1   = (const float*)d_in[6];   // [1536][768]
    const float* b1   = (const float*)d_in[7];
    const float* W2   = (const float*)d_in[8];   // [768][384]
    const float* b2   = (const float*)d_in[9];
    const float* W3   = (const float*)d_in[10];
    const float* b3   = (const float*)d_in[11];
    float* out = (float*)d_out;

    float* fws      = (float*)d_ws;
    float* dscale   = fws;                 // 2048
    float* sscale   = dscale + 2048;       // 512
    float* smean    = sscale + 512;        // 512
    float* cscale   = smean + 512;         // 512
    float* predv    = cscale + 512;        // 512
    float* dcws     = predv + 512;         // 512
    float* Rws      = dcws + 512;          // 8192
    unsigned short* docB  = (unsigned short*)(Rws + 8192);
    unsigned short* segB  = docB + (size_t)2048 * 768;
    unsigned short* W1T   = segB + (size_t)512 * 768;     // [768][1536]
    unsigned short* W2T   = W1T + (size_t)768 * 1536;     // [384][768]
    unsigned short* XdocB = W2T + (size_t)384 * 768;      // [2048][768]
    unsigned short* XsegB = XdocB + (size_t)2048 * 768;   // [512][768]

    k_prep<<<1001, 256, 0, stream>>>(doc, seg, W1, W2, tagg, tis, ns,
                                     dscale, sscale, smean, cscale,
                                     docB, segB, W1T, W2T, out);
    k_l1<<<dim3(40, 6), 256, 0, stream>>>(docB, segB, W1T, b1, XdocB, XsegB);
    k_fused_mfma<<<576, 256, 0, stream>>>(XdocB, XsegB, W2T, b2, W3, b3, nd, ns,
                                          docB, segB, seg, dscale, sscale,
                                          smean, cscale, out + 544, predv,
                                          dcws, Rws);
    k_final<<<1, 256, 0, stream>>>(ns, dcws, Rws, predv, out);
}